// Round 2
// baseline (8935.406 us; speedup 1.0000x reference)
//
#include <hip/hip_runtime.h>

#define NN 16384
#define NE 262144
#define TWC 25
#define HC 128
#define NBC 8
#define LC 6
#define MINC 284
#define UINC 257
#define EINC 28
#define EPSC 1e-5
#define DTC 0.01f
#define SP 65  // padded LDS row stride (floats) -> conflict-free stage writes

// 32-FMA register-tile step: 4 edges x 8 channels, fp64 accumulate
#define FMA32D(ACC, A0, A1, A2, A3, W0, W1_)                          \
  do {                                                                \
    double wv[8] = {(double)W0.x, (double)W0.y, (double)W0.z,         \
                    (double)W0.w, (double)W1_.x, (double)W1_.y,       \
                    (double)W1_.z, (double)W1_.w};                    \
    double av[4] = {(double)A0, (double)A1, (double)A2, (double)A3};  \
    _Pragma("unroll") for (int i_ = 0; i_ < 4; ++i_)                  \
      _Pragma("unroll") for (int j_ = 0; j_ < 8; ++j_)                \
        ACC[i_][j_] = fma(av[i_], wv[j_], ACC[i_][j_]);               \
  } while (0)

__global__ __launch_bounds__(256) void k_deg(const int* __restrict__ dst,
                                             float* __restrict__ deg) {
  int e = blockIdx.x * 256 + threadIdx.x;
  if (e < NE) atomicAdd(&deg[dst[e]], 1.0f);
}

__global__ __launch_bounds__(256) void k_rdeg(float* deg) {
  int n = blockIdx.x * 256 + threadIdx.x;
  if (n < NN) deg[n] = 1.0f / fmaxf(deg[n], 1.0f);
}

__global__ __launch_bounds__(256) void k_cntb(const int* __restrict__ batch,
                                              float* __restrict__ cntb) {
  int n = blockIdx.x * 256 + threadIdx.x;
  int b = (n < NN) ? batch[n] : -1;
#pragma unroll
  for (int bb = 0; bb < NBC; ++bb) {
    unsigned long long m = __ballot(b == bb);
    if ((threadIdx.x & 63) == 0 && m != 0ULL)
      atomicAdd(&cntb[bb], (float)__popcll(m));
  }
}

// node embedding: [u(25), pos_sp(2), var(1)] -> 128 -> 128, relu both
__global__ __launch_bounds__(256) void k_emb(
    const float* __restrict__ u, const float* __restrict__ pos,
    const float* __restrict__ W1, const float* __restrict__ b1,
    const float* __restrict__ W2, const float* __restrict__ b2,
    float* __restrict__ h) {
  __shared__ float sin_[2][EINC];
  __shared__ float shid[2][HC];
  int n0 = blockIdx.x * 2;
  int t = threadIdx.x;
  if (t < 2 * EINC) {
    int e = t / EINC, c = t - e * EINC;
    int n = n0 + e;
    float v;
    if (c < TWC) v = u[n * TWC + c];
    else if (c == TWC) v = pos[n * 3 + 1];
    else if (c == TWC + 1) v = pos[n * 3 + 2];
    else v = pos[n * 3 + 0];
    sin_[e][c] = v;
  }
  __syncthreads();
  int e = t >> 7, j = t & 127;
  double acc = (double)b1[j];
  for (int k = 0; k < EINC; ++k)
    acc = fma((double)sin_[e][k], (double)W1[k * HC + j], acc);
  shid[e][j] = fmaxf((float)acc, 0.f);
  __syncthreads();
  double acc2 = (double)b2[j];
  for (int k = 0; k < HC; ++k)
    acc2 = fma((double)shid[e][k], (double)W2[k * HC + j], acc2);
  h[(n0 + e) * HC + j] = fmaxf((float)acc2, 0.f);
}

// edge message MLP 284->128->128 (relu both) + atomic scatter into agg
__global__ __launch_bounds__(256) void k_msg(
    const float* __restrict__ h, const float* __restrict__ u,
    const float* __restrict__ pos, const int* __restrict__ src,
    const int* __restrict__ dst, const float* __restrict__ W1,
    const float* __restrict__ b1, const float* __restrict__ W2,
    const float* __restrict__ b2, float* __restrict__ agg) {
  __shared__ float sm[156 * SP];
  const int t = threadIdx.x;
  const int e_base = blockIdx.x * 64;
  const int eg = t >> 4, jg = t & 15;
  const int e0 = eg * 4, j0 = jg * 8;
  const int half = t >> 7, col = t & 127;

  double acc[4][8];
#pragma unroll
  for (int jj = 0; jj < 8; ++jj) {
    double bv = (double)b1[j0 + jj];
#pragma unroll
    for (int i = 0; i < 4; ++i) acc[i][jj] = bv;
  }

  // chunk A: m_in rows 0..127 = h[dst], staged transposed sm[k][e]
  for (int it = 0; it < 32; ++it) {
    int e = 2 * it + half;
    int n = dst[e_base + e];
    sm[col * SP + e] = h[n * HC + col];
  }
  __syncthreads();

  const float4* W1v = (const float4*)W1;
#pragma unroll 4
  for (int k = 0; k < 128; ++k) {
    float a0 = sm[k * SP + e0 + 0];
    float a1 = sm[k * SP + e0 + 1];
    float a2 = sm[k * SP + e0 + 2];
    float a3 = sm[k * SP + e0 + 3];
    float4 w0 = W1v[k * 32 + jg * 2];
    float4 w1 = W1v[k * 32 + jg * 2 + 1];
    FMA32D(acc, a0, a1, a2, a3, w0, w1);
  }
  __syncthreads();

  // chunk B: rows 128..283 (local 0..155) = h[src], u-diff, pos-diff, var
  for (int it = 0; it < 32; ++it) {
    int e = 2 * it + half;
    int n = src[e_base + e];
    sm[col * SP + e] = h[n * HC + col];
  }
  for (int idx = t; idx < 64 * 28; idx += 256) {
    int e = idx / 28;
    int c = idx - e * 28;
    int ge = e_base + e;
    int nd = dst[ge], ns = src[ge];
    float v;
    if (c < TWC) v = u[nd * TWC + c] - u[ns * TWC + c];
    else if (c == TWC) v = pos[nd * 3 + 1] - pos[ns * 3 + 1];
    else if (c == TWC + 1) v = pos[nd * 3 + 2] - pos[ns * 3 + 2];
    else v = pos[nd * 3 + 0];
    sm[(128 + c) * SP + e] = v;
  }
  __syncthreads();

#pragma unroll 4
  for (int k = 0; k < 156; ++k) {
    float a0 = sm[k * SP + e0 + 0];
    float a1 = sm[k * SP + e0 + 1];
    float a2 = sm[k * SP + e0 + 2];
    float a3 = sm[k * SP + e0 + 3];
    float4 w0 = W1v[(128 + k) * 32 + jg * 2];
    float4 w1 = W1v[(128 + k) * 32 + jg * 2 + 1];
    FMA32D(acc, a0, a1, a2, a3, w0, w1);
  }
  __syncthreads();

  // hidden (relu) -> sm rows 0..127
#pragma unroll
  for (int jj = 0; jj < 8; ++jj) {
#pragma unroll
    for (int i = 0; i < 4; ++i)
      sm[(j0 + jj) * SP + e0 + i] = fmaxf((float)acc[i][jj], 0.f);
  }
  __syncthreads();

  double acc2[4][8];
#pragma unroll
  for (int jj = 0; jj < 8; ++jj) {
    double bv = (double)b2[j0 + jj];
#pragma unroll
    for (int i = 0; i < 4; ++i) acc2[i][jj] = bv;
  }
  const float4* W2v = (const float4*)W2;
#pragma unroll 4
  for (int k = 0; k < 128; ++k) {
    float a0 = sm[k * SP + e0 + 0];
    float a1 = sm[k * SP + e0 + 1];
    float a2 = sm[k * SP + e0 + 2];
    float a3 = sm[k * SP + e0 + 3];
    float4 w0 = W2v[k * 32 + jg * 2];
    float4 w1 = W2v[k * 32 + jg * 2 + 1];
    FMA32D(acc2, a0, a1, a2, a3, w0, w1);
  }

#pragma unroll
  for (int i = 0; i < 4; ++i) {
    int d = dst[e_base + e0 + i];
    float* basep = agg + d * HC + j0;
#pragma unroll
    for (int jj = 0; jj < 8; ++jj)
      atomicAdd(basep + jj, fmaxf((float)acc2[i][jj], 0.f));
  }
}

// node update MLP 257->128->128 (relu both); hn = h + upd
__global__ __launch_bounds__(256) void k_upd(
    const float* __restrict__ h, const float* __restrict__ pos,
    const float* __restrict__ agg, const float* __restrict__ rdeg,
    const float* __restrict__ W1, const float* __restrict__ b1,
    const float* __restrict__ W2, const float* __restrict__ b2,
    float* __restrict__ hn) {
  __shared__ float sm[129 * SP];
  const int t = threadIdx.x;
  const int n_base = blockIdx.x * 64;
  const int eg = t >> 4, jg = t & 15;
  const int e0 = eg * 4, j0 = jg * 8;
  const int half = t >> 7, col = t & 127;

  double acc[4][8];
#pragma unroll
  for (int jj = 0; jj < 8; ++jj) {
    double bv = (double)b1[j0 + jj];
#pragma unroll
    for (int i = 0; i < 4; ++i) acc[i][jj] = bv;
  }

  // chunk A: rows 0..127 = h[n]
  for (int it = 0; it < 32; ++it) {
    int e = 2 * it + half;
    sm[col * SP + e] = h[(n_base + e) * HC + col];
  }
  __syncthreads();

  const float4* W1v = (const float4*)W1;
#pragma unroll 4
  for (int k = 0; k < 128; ++k) {
    float a0 = sm[k * SP + e0 + 0];
    float a1 = sm[k * SP + e0 + 1];
    float a2 = sm[k * SP + e0 + 2];
    float a3 = sm[k * SP + e0 + 3];
    float4 w0 = W1v[k * 32 + jg * 2];
    float4 w1 = W1v[k * 32 + jg * 2 + 1];
    FMA32D(acc, a0, a1, a2, a3, w0, w1);
  }
  __syncthreads();

  // chunk B: rows 128..256 (local 0..128) = agg/deg (128) + var (1)
  for (int it = 0; it < 32; ++it) {
    int e = 2 * it + half;
    int n = n_base + e;
    sm[col * SP + e] = agg[n * HC + col] * rdeg[n];
  }
  if (t < 64) sm[128 * SP + t] = pos[(n_base + t) * 3 + 0];
  __syncthreads();

#pragma unroll 4
  for (int k = 0; k < 129; ++k) {
    float a0 = sm[k * SP + e0 + 0];
    float a1 = sm[k * SP + e0 + 1];
    float a2 = sm[k * SP + e0 + 2];
    float a3 = sm[k * SP + e0 + 3];
    float4 w0 = W1v[(128 + k) * 32 + jg * 2];
    float4 w1 = W1v[(128 + k) * 32 + jg * 2 + 1];
    FMA32D(acc, a0, a1, a2, a3, w0, w1);
  }
  __syncthreads();

#pragma unroll
  for (int jj = 0; jj < 8; ++jj) {
#pragma unroll
    for (int i = 0; i < 4; ++i)
      sm[(j0 + jj) * SP + e0 + i] = fmaxf((float)acc[i][jj], 0.f);
  }
  __syncthreads();

  double acc2[4][8];
#pragma unroll
  for (int jj = 0; jj < 8; ++jj) {
    double bv = (double)b2[j0 + jj];
#pragma unroll
    for (int i = 0; i < 4; ++i) acc2[i][jj] = bv;
  }
  const float4* W2v = (const float4*)W2;
#pragma unroll 4
  for (int k = 0; k < 128; ++k) {
    float a0 = sm[k * SP + e0 + 0];
    float a1 = sm[k * SP + e0 + 1];
    float a2 = sm[k * SP + e0 + 2];
    float a3 = sm[k * SP + e0 + 3];
    float4 w0 = W2v[k * 32 + jg * 2];
    float4 w1 = W2v[k * 32 + jg * 2 + 1];
    FMA32D(acc2, a0, a1, a2, a3, w0, w1);
  }

#pragma unroll
  for (int i = 0; i < 4; ++i) {
    int n = n_base + e0 + i;
#pragma unroll
    for (int jj = 0; jj < 8; ++jj) {
      int j = j0 + jj;
      hn[n * HC + j] = h[n * HC + j] + fmaxf((float)acc2[i][jj], 0.f);
    }
  }
}

// per-(batch,channel) sum & sumsq (fp64) with run-length accumulation
__global__ __launch_bounds__(256) void k_stats(const float* __restrict__ hn,
                                               const int* __restrict__ batch,
                                               double* __restrict__ stats) {
  int n0 = blockIdx.x * 32;
  int ch = threadIdx.x & 127;
  int rh = threadIdx.x >> 7;
  double s = 0.0, ss = 0.0;
  int cur = batch[n0 + rh];
  for (int r = rh; r < 32; r += 2) {
    int n = n0 + r;
    int b = batch[n];
    double v = (double)hn[n * HC + ch];
    if (b != cur) {
      atomicAdd(&stats[cur * HC + ch], s);
      atomicAdd(&stats[NBC * HC + cur * HC + ch], ss);
      s = 0.0; ss = 0.0; cur = b;
    }
    s += v;
    ss += v * v;
  }
  atomicAdd(&stats[cur * HC + ch], s);
  atomicAdd(&stats[NBC * HC + cur * HC + ch], ss);
}

__global__ __launch_bounds__(256) void k_norm(
    const float* __restrict__ hn, const int* __restrict__ batch,
    const double* __restrict__ stats, const float* __restrict__ cntb,
    float* __restrict__ hout) {
  int idx = blockIdx.x * 256 + threadIdx.x;
  int n = idx >> 7, ch = idx & 127;
  int b = batch[n];
  double c = fmax((double)cntb[b], 1.0);
  double mean = stats[b * HC + ch] / c;
  double ms = stats[NBC * HC + b * HC + ch] / c;
  double var = fmax(ms - mean * mean, 0.0);
  hout[idx] = (float)(((double)hn[idx] - mean) / sqrt(var + EPSC));
}

// conv head: 1x128 -> conv(8,k15,s4) relu -> conv(4,k10,s2) relu -> conv(1,k10,s1)
__global__ __launch_bounds__(64) void k_head(
    const float* __restrict__ h, const float* __restrict__ u,
    const float* __restrict__ c1W, const float* __restrict__ c1b,
    const float* __restrict__ c2W, const float* __restrict__ c2b,
    const float* __restrict__ c3W, const float* __restrict__ c3b,
    float* __restrict__ out) {
  __shared__ float hr[128];
  __shared__ float y1[8 * 29];
  __shared__ float y2[4 * 10];
  __shared__ float dv;
  int n = blockIdx.x, t = threadIdx.x;
  hr[t] = h[n * HC + t];
  hr[t + 64] = h[n * HC + 64 + t];
  __syncthreads();
  for (int idx = t; idx < 8 * 29; idx += 64) {
    int o = idx / 29, p = idx - o * 29;
    float acc = c1b[o];
    for (int q = 0; q < 15; ++q) acc = fmaf(hr[p * 4 + q], c1W[o * 15 + q], acc);
    y1[o * 29 + p] = fmaxf(acc, 0.f);
  }
  __syncthreads();
  if (t < 40) {
    int o = t / 10, p = t - o * 10;
    float acc = c2b[o];
    for (int i = 0; i < 8; ++i)
      for (int q = 0; q < 10; ++q)
        acc = fmaf(y1[i * 29 + p * 2 + q], c2W[o * 80 + i * 10 + q], acc);
    y2[o * 10 + p] = fmaxf(acc, 0.f);
  }
  __syncthreads();
  if (t == 0) {
    float acc = c3b[0];
    for (int i = 0; i < 4; ++i)
      for (int q = 0; q < 10; ++q)
        acc = fmaf(y2[i * 10 + q], c3W[i * 10 + q], acc);
    dv = acc;
  }
  __syncthreads();
  if (t < TWC) out[n * TWC + t] = u[n * TWC + 24] + DTC * (float)(t + 1) * dv;
}

extern "C" void kernel_launch(void* const* d_in, const int* in_sizes, int n_in,
                              void* d_out, int out_size, void* d_ws,
                              size_t ws_size, hipStream_t stream) {
  const float* u = (const float*)d_in[0];
  const float* pos = (const float*)d_in[1];
  const int* ei = (const int*)d_in[2];
  const int* batch = (const int*)d_in[3];
  const float* eW1 = (const float*)d_in[4];
  const float* eb1 = (const float*)d_in[5];
  const float* eW2 = (const float*)d_in[6];
  const float* eb2 = (const float*)d_in[7];
  const float* mW1 = (const float*)d_in[8];
  const float* mb1 = (const float*)d_in[9];
  const float* mW2 = (const float*)d_in[10];
  const float* mb2 = (const float*)d_in[11];
  const float* uW1 = (const float*)d_in[12];
  const float* ub1 = (const float*)d_in[13];
  const float* uW2 = (const float*)d_in[14];
  const float* ub2 = (const float*)d_in[15];
  const float* c1W = (const float*)d_in[16];
  const float* c1b = (const float*)d_in[17];
  const float* c2W = (const float*)d_in[18];
  const float* c2b = (const float*)d_in[19];
  const float* c3W = (const float*)d_in[20];
  const float* c3b = (const float*)d_in[21];
  float* out = (float*)d_out;

  const int* srcI = ei;
  const int* dstI = ei + NE;

  // doubles first for 8B alignment
  double* statsd = (double*)d_ws;                    // 2*NBC*HC doubles
  float* h = (float*)(statsd + 2 * NBC * HC);        // NN*HC
  float* hn = h + NN * HC;                           // NN*HC
  float* agg = hn + NN * HC;                         // NN*HC
  float* deg = agg + NN * HC;                        // NN
  float* cntb = deg + NN;                            // NBC

  hipMemsetAsync(deg, 0, NN * sizeof(float), stream);
  hipMemsetAsync(cntb, 0, NBC * sizeof(float), stream);
  k_deg<<<NE / 256, 256, 0, stream>>>(dstI, deg);
  k_rdeg<<<NN / 256, 256, 0, stream>>>(deg);
  k_cntb<<<NN / 256, 256, 0, stream>>>(batch, cntb);
  k_emb<<<NN / 2, 256, 0, stream>>>(u, pos, eW1, eb1, eW2, eb2, h);

  for (int l = 0; l < LC; ++l) {
    hipMemsetAsync(agg, 0, (size_t)NN * HC * sizeof(float), stream);
    hipMemsetAsync(statsd, 0, 2 * NBC * HC * sizeof(double), stream);
    k_msg<<<NE / 64, 256, 0, stream>>>(h, u, pos, srcI, dstI,
                                       mW1 + (size_t)l * MINC * HC, mb1 + l * HC,
                                       mW2 + (size_t)l * HC * HC, mb2 + l * HC,
                                       agg);
    k_upd<<<NN / 64, 256, 0, stream>>>(h, pos, agg, deg,
                                       uW1 + (size_t)l * UINC * HC, ub1 + l * HC,
                                       uW2 + (size_t)l * HC * HC, ub2 + l * HC,
                                       hn);
    k_stats<<<NN / 32, 256, 0, stream>>>(hn, batch, statsd);
    k_norm<<<NN * HC / 256, 256, 0, stream>>>(hn, batch, statsd, cntb, h);
  }
  k_head<<<NN, 64, 0, stream>>>(h, u, c1W, c1b, c2W, c2b, c3W, c3b, out);
}

// Round 3
// 4577.385 us; speedup vs baseline: 1.9521x; 1.9521x over previous
//
#include <hip/hip_runtime.h>

#define NN 16384
#define NE 262144
#define TWC 25
#define HC 128
#define NBC 8
#define LC 6
#define MINC 284
#define UINC 257
#define EINC 28
#define EPSC 1e-5
#define DTC 0.01f
#define SP 65  // padded LDS row stride (floats) -> conflict-free

// fp32 register-tile FMA step: 4 edges x 8 channels
#define FMA32F(ACCF, A0, A1, A2, A3, W0, W1_)                  \
  do {                                                         \
    float wv[8] = {W0.x, W0.y, W0.z, W0.w,                     \
                   W1_.x, W1_.y, W1_.z, W1_.w};                \
    float av[4] = {A0, A1, A2, A3};                            \
    _Pragma("unroll") for (int i_ = 0; i_ < 4; ++i_)           \
      _Pragma("unroll") for (int j_ = 0; j_ < 8; ++j_)         \
        ACCF[i_][j_] = fmaf(av[i_], wv[j_], ACCF[i_][j_]);     \
  } while (0)

// flush fp32 partials into fp64 accumulators (chunked accumulation)
#define FLUSH32(ACCD, ACCF)                                    \
  do {                                                         \
    _Pragma("unroll") for (int i_ = 0; i_ < 4; ++i_)           \
      _Pragma("unroll") for (int j_ = 0; j_ < 8; ++j_) {       \
        ACCD[i_][j_] += (double)ACCF[i_][j_];                  \
        ACCF[i_][j_] = 0.f;                                    \
      }                                                        \
  } while (0)

#define KSTEP(ACCF, WV, ROW, KW)                               \
  do {                                                         \
    float a0_ = sm[(ROW) * SP + e0 + 0];                       \
    float a1_ = sm[(ROW) * SP + e0 + 1];                       \
    float a2_ = sm[(ROW) * SP + e0 + 2];                       \
    float a3_ = sm[(ROW) * SP + e0 + 3];                       \
    float4 w0_ = WV[(KW) * 32 + jg * 2];                       \
    float4 w1_ = WV[(KW) * 32 + jg * 2 + 1];                   \
    FMA32F(ACCF, a0_, a1_, a2_, a3_, w0_, w1_);                \
  } while (0)

// ---------- preprocessing: counting sort of edges by dst ----------

__global__ __launch_bounds__(256) void k_cnt(const int* __restrict__ dst,
                                             int* __restrict__ cnt) {
  int e = blockIdx.x * 256 + threadIdx.x;
  if (e < NE) atomicAdd(&cnt[dst[e]], 1);
}

__global__ __launch_bounds__(256) void k_scan(const int* __restrict__ cnt,
                                              int* __restrict__ rowptr,
                                              int* __restrict__ fill) {
  __shared__ int part[256];
  int t = threadIdx.x;
  int s = 0;
  for (int i = 0; i < 64; ++i) s += cnt[t * 64 + i];
  part[t] = s;
  __syncthreads();
  if (t == 0) {
    int r = 0;
    for (int i = 0; i < 256; ++i) { int v = part[i]; part[i] = r; r += v; }
  }
  __syncthreads();
  int r = part[t];
  for (int i = 0; i < 64; ++i) {
    int n = t * 64 + i;
    rowptr[n] = r;
    fill[n] = r;
    r += cnt[n];
  }
  if (t == 255) rowptr[NN] = r;
}

__global__ __launch_bounds__(256) void k_scatter(const int* __restrict__ src,
                                                 const int* __restrict__ dst,
                                                 int* __restrict__ fill,
                                                 int* __restrict__ srcS,
                                                 int* __restrict__ dstS) {
  int e = blockIdx.x * 256 + threadIdx.x;
  if (e < NE) {
    int d = dst[e];
    int p = atomicAdd(&fill[d], 1);
    srcS[p] = src[e];
    dstS[p] = d;
  }
}

__global__ __launch_bounds__(256) void k_rdeg(const int* __restrict__ rowptr,
                                              float* __restrict__ rdeg) {
  int n = blockIdx.x * 256 + threadIdx.x;
  if (n < NN) {
    int c = rowptr[n + 1] - rowptr[n];
    rdeg[n] = 1.0f / (float)max(c, 1);
  }
}

__global__ __launch_bounds__(256) void k_cntb(const int* __restrict__ batch,
                                              float* __restrict__ cntb) {
  int n = blockIdx.x * 256 + threadIdx.x;
  int b = (n < NN) ? batch[n] : -1;
#pragma unroll
  for (int bb = 0; bb < NBC; ++bb) {
    unsigned long long m = __ballot(b == bb);
    if ((threadIdx.x & 63) == 0 && m != 0ULL)
      atomicAdd(&cntb[bb], (float)__popcll(m));
  }
}

// node embedding: [u(25), pos_sp(2), var(1)] -> 128 -> 128, relu both
__global__ __launch_bounds__(256) void k_emb(
    const float* __restrict__ u, const float* __restrict__ pos,
    const float* __restrict__ W1, const float* __restrict__ b1,
    const float* __restrict__ W2, const float* __restrict__ b2,
    float* __restrict__ h) {
  __shared__ float sin_[2][EINC];
  __shared__ float shid[2][HC];
  int n0 = blockIdx.x * 2;
  int t = threadIdx.x;
  if (t < 2 * EINC) {
    int e = t / EINC, c = t - e * EINC;
    int n = n0 + e;
    float v;
    if (c < TWC) v = u[n * TWC + c];
    else if (c == TWC) v = pos[n * 3 + 1];
    else if (c == TWC + 1) v = pos[n * 3 + 2];
    else v = pos[n * 3 + 0];
    sin_[e][c] = v;
  }
  __syncthreads();
  int e = t >> 7, j = t & 127;
  double acc = (double)b1[j];
  for (int k = 0; k < EINC; ++k)
    acc = fma((double)sin_[e][k], (double)W1[k * HC + j], acc);
  shid[e][j] = fmaxf((float)acc, 0.f);
  __syncthreads();
  double acc2 = (double)b2[j];
  for (int k = 0; k < HC; ++k)
    acc2 = fma((double)shid[e][k], (double)W2[k * HC + j], acc2);
  h[(n0 + e) * HC + j] = fmaxf((float)acc2, 0.f);
}

// edge message MLP 284->128->128 on dst-sorted edges + segmented reduction
__global__ __launch_bounds__(256) void k_msg(
    const float* __restrict__ h, const float* __restrict__ u,
    const float* __restrict__ pos, const int* __restrict__ srcS,
    const int* __restrict__ dstS, const float* __restrict__ W1,
    const float* __restrict__ b1, const float* __restrict__ W2,
    const float* __restrict__ b2, float* __restrict__ agg) {
  __shared__ float sm[156 * SP];
  __shared__ int sdst[64];
  __shared__ int ssrc[64];
  const int t = threadIdx.x;
  const int e_base = blockIdx.x * 64;
  const int eg = t >> 4, jg = t & 15;
  const int e0 = eg * 4, j0 = jg * 8;
  const int half = t >> 7, col = t & 127;

  if (t < 64) {
    sdst[t] = dstS[e_base + t];
    ssrc[t] = srcS[e_base + t];
  }
  __syncthreads();

  float accf[4][8];
  double accd[4][8];
#pragma unroll
  for (int jj = 0; jj < 8; ++jj) {
    double bv = (double)b1[j0 + jj];
#pragma unroll
    for (int i = 0; i < 4; ++i) { accd[i][jj] = bv; accf[i][jj] = 0.f; }
  }

  // chunk A: m_in rows 0..127 = h[dst], staged transposed sm[k][e]
  for (int it = 0; it < 32; ++it) {
    int e = 2 * it + half;
    sm[col * SP + e] = h[sdst[e] * HC + col];
  }
  __syncthreads();

  const float4* W1v = (const float4*)W1;
  for (int kc = 0; kc < 128; kc += 16) {
#pragma unroll
    for (int kk = 0; kk < 16; ++kk) KSTEP(accf, W1v, kc + kk, kc + kk);
    FLUSH32(accd, accf);
  }
  __syncthreads();

  // chunk B: rows 128..283 (local 0..155) = h[src], u-diff, pos-diff, var
  for (int it = 0; it < 32; ++it) {
    int e = 2 * it + half;
    sm[col * SP + e] = h[ssrc[e] * HC + col];
  }
  for (int idx = t; idx < 64 * 28; idx += 256) {
    int e = idx / 28;
    int c = idx - e * 28;
    int nd = sdst[e], ns = ssrc[e];
    float v;
    if (c < TWC) v = u[nd * TWC + c] - u[ns * TWC + c];
    else if (c == TWC) v = pos[nd * 3 + 1] - pos[ns * 3 + 1];
    else if (c == TWC + 1) v = pos[nd * 3 + 2] - pos[ns * 3 + 2];
    else v = pos[nd * 3 + 0];
    sm[(128 + c) * SP + e] = v;
  }
  __syncthreads();

  for (int kc = 0; kc < 144; kc += 16) {
#pragma unroll
    for (int kk = 0; kk < 16; ++kk) KSTEP(accf, W1v, kc + kk, 128 + kc + kk);
    FLUSH32(accd, accf);
  }
#pragma unroll
  for (int kk = 0; kk < 12; ++kk) KSTEP(accf, W1v, 144 + kk, 272 + kk);
  FLUSH32(accd, accf);
  __syncthreads();

  // hidden (relu) -> sm rows 0..127
#pragma unroll
  for (int jj = 0; jj < 8; ++jj) {
#pragma unroll
    for (int i = 0; i < 4; ++i)
      sm[(j0 + jj) * SP + e0 + i] = fmaxf((float)accd[i][jj], 0.f);
  }
  __syncthreads();

  // GEMM2 (reuse accf/accd)
#pragma unroll
  for (int jj = 0; jj < 8; ++jj) {
    double bv = (double)b2[j0 + jj];
#pragma unroll
    for (int i = 0; i < 4; ++i) { accd[i][jj] = bv; accf[i][jj] = 0.f; }
  }
  const float4* W2v = (const float4*)W2;
  for (int kc = 0; kc < 128; kc += 16) {
#pragma unroll
    for (int kk = 0; kk < 16; ++kk) KSTEP(accf, W2v, kc + kk, kc + kk);
    FLUSH32(accd, accf);
  }
  __syncthreads();

  // msg (relu) -> sm[j][e]
#pragma unroll
  for (int jj = 0; jj < 8; ++jj) {
#pragma unroll
    for (int i = 0; i < 4; ++i)
      sm[(j0 + jj) * SP + e0 + i] = fmaxf((float)accd[i][jj], 0.f);
  }
  __syncthreads();

  // segmented reduction over sorted dst runs: one atomic per (run, channel)
  {
    int j = t & 127;
    int ebeg = (t >> 7) * 32;
    float s = 0.f;
    int cur = sdst[ebeg];
    for (int e = ebeg; e < ebeg + 32; ++e) {
      int d = sdst[e];  // wave-uniform
      if (d != cur) {
        atomicAdd(&agg[cur * HC + j], s);
        s = 0.f;
        cur = d;
      }
      s += sm[j * SP + e];
    }
    atomicAdd(&agg[cur * HC + j], s);
  }
}

// node update MLP 257->128->128 (relu both); hn = h + upd
__global__ __launch_bounds__(256) void k_upd(
    const float* __restrict__ h, const float* __restrict__ pos,
    const float* __restrict__ agg, const float* __restrict__ rdeg,
    const float* __restrict__ W1, const float* __restrict__ b1,
    const float* __restrict__ W2, const float* __restrict__ b2,
    float* __restrict__ hn) {
  __shared__ float sm[129 * SP];
  const int t = threadIdx.x;
  const int n_base = blockIdx.x * 64;
  const int eg = t >> 4, jg = t & 15;
  const int e0 = eg * 4, j0 = jg * 8;
  const int half = t >> 7, col = t & 127;

  float accf[4][8];
  double accd[4][8];
#pragma unroll
  for (int jj = 0; jj < 8; ++jj) {
    double bv = (double)b1[j0 + jj];
#pragma unroll
    for (int i = 0; i < 4; ++i) { accd[i][jj] = bv; accf[i][jj] = 0.f; }
  }

  // chunk A: rows 0..127 = h[n]
  for (int it = 0; it < 32; ++it) {
    int e = 2 * it + half;
    sm[col * SP + e] = h[(n_base + e) * HC + col];
  }
  __syncthreads();

  const float4* W1v = (const float4*)W1;
  for (int kc = 0; kc < 128; kc += 16) {
#pragma unroll
    for (int kk = 0; kk < 16; ++kk) KSTEP(accf, W1v, kc + kk, kc + kk);
    FLUSH32(accd, accf);
  }
  __syncthreads();

  // chunk B: rows 128..256 (local 0..128) = agg/deg (128) + var (1)
  for (int it = 0; it < 32; ++it) {
    int e = 2 * it + half;
    int n = n_base + e;
    sm[col * SP + e] = agg[n * HC + col] * rdeg[n];
  }
  if (t < 64) sm[128 * SP + t] = pos[(n_base + t) * 3 + 0];
  __syncthreads();

  for (int kc = 0; kc < 128; kc += 16) {
#pragma unroll
    for (int kk = 0; kk < 16; ++kk) KSTEP(accf, W1v, kc + kk, 128 + kc + kk);
    FLUSH32(accd, accf);
  }
  KSTEP(accf, W1v, 128, 256);
  FLUSH32(accd, accf);
  __syncthreads();

#pragma unroll
  for (int jj = 0; jj < 8; ++jj) {
#pragma unroll
    for (int i = 0; i < 4; ++i)
      sm[(j0 + jj) * SP + e0 + i] = fmaxf((float)accd[i][jj], 0.f);
  }
  __syncthreads();

#pragma unroll
  for (int jj = 0; jj < 8; ++jj) {
    double bv = (double)b2[j0 + jj];
#pragma unroll
    for (int i = 0; i < 4; ++i) { accd[i][jj] = bv; accf[i][jj] = 0.f; }
  }
  const float4* W2v = (const float4*)W2;
  for (int kc = 0; kc < 128; kc += 16) {
#pragma unroll
    for (int kk = 0; kk < 16; ++kk) KSTEP(accf, W2v, kc + kk, kc + kk);
    FLUSH32(accd, accf);
  }

#pragma unroll
  for (int i = 0; i < 4; ++i) {
    int n = n_base + e0 + i;
#pragma unroll
    for (int jj = 0; jj < 8; ++jj) {
      int j = j0 + jj;
      hn[n * HC + j] = h[n * HC + j] + fmaxf((float)accd[i][jj], 0.f);
    }
  }
}

// per-(batch,channel) sum & sumsq (fp64) with run-length accumulation
__global__ __launch_bounds__(256) void k_stats(const float* __restrict__ hn,
                                               const int* __restrict__ batch,
                                               double* __restrict__ stats) {
  int n0 = blockIdx.x * 32;
  int ch = threadIdx.x & 127;
  int rh = threadIdx.x >> 7;
  double s = 0.0, ss = 0.0;
  int cur = batch[n0 + rh];
  for (int r = rh; r < 32; r += 2) {
    int n = n0 + r;
    int b = batch[n];
    double v = (double)hn[n * HC + ch];
    if (b != cur) {
      atomicAdd(&stats[cur * HC + ch], s);
      atomicAdd(&stats[NBC * HC + cur * HC + ch], ss);
      s = 0.0; ss = 0.0; cur = b;
    }
    s += v;
    ss += v * v;
  }
  atomicAdd(&stats[cur * HC + ch], s);
  atomicAdd(&stats[NBC * HC + cur * HC + ch], ss);
}

__global__ __launch_bounds__(256) void k_norm(
    const float* __restrict__ hn, const int* __restrict__ batch,
    const double* __restrict__ stats, const float* __restrict__ cntb,
    float* __restrict__ hout) {
  int idx = blockIdx.x * 256 + threadIdx.x;
  int n = idx >> 7, ch = idx & 127;
  int b = batch[n];
  double c = fmax((double)cntb[b], 1.0);
  double mean = stats[b * HC + ch] / c;
  double ms = stats[NBC * HC + b * HC + ch] / c;
  double var = fmax(ms - mean * mean, 0.0);
  hout[idx] = (float)(((double)hn[idx] - mean) / sqrt(var + EPSC));
}

// conv head: 1x128 -> conv(8,k15,s4) relu -> conv(4,k10,s2) relu -> conv(1,k10,s1)
__global__ __launch_bounds__(64) void k_head(
    const float* __restrict__ h, const float* __restrict__ u,
    const float* __restrict__ c1W, const float* __restrict__ c1b,
    const float* __restrict__ c2W, const float* __restrict__ c2b,
    const float* __restrict__ c3W, const float* __restrict__ c3b,
    float* __restrict__ out) {
  __shared__ float hr[128];
  __shared__ float y1[8 * 29];
  __shared__ float y2[4 * 10];
  __shared__ float dv;
  int n = blockIdx.x, t = threadIdx.x;
  hr[t] = h[n * HC + t];
  hr[t + 64] = h[n * HC + 64 + t];
  __syncthreads();
  for (int idx = t; idx < 8 * 29; idx += 64) {
    int o = idx / 29, p = idx - o * 29;
    float acc = c1b[o];
    for (int q = 0; q < 15; ++q) acc = fmaf(hr[p * 4 + q], c1W[o * 15 + q], acc);
    y1[o * 29 + p] = fmaxf(acc, 0.f);
  }
  __syncthreads();
  if (t < 40) {
    int o = t / 10, p = t - o * 10;
    float acc = c2b[o];
    for (int i = 0; i < 8; ++i)
      for (int q = 0; q < 10; ++q)
        acc = fmaf(y1[i * 29 + p * 2 + q], c2W[o * 80 + i * 10 + q], acc);
    y2[o * 10 + p] = fmaxf(acc, 0.f);
  }
  __syncthreads();
  if (t == 0) {
    float acc = c3b[0];
    for (int i = 0; i < 4; ++i)
      for (int q = 0; q < 10; ++q)
        acc = fmaf(y2[i * 10 + q], c3W[i * 10 + q], acc);
    dv = acc;
  }
  __syncthreads();
  if (t < TWC) out[n * TWC + t] = u[n * TWC + 24] + DTC * (float)(t + 1) * dv;
}

extern "C" void kernel_launch(void* const* d_in, const int* in_sizes, int n_in,
                              void* d_out, int out_size, void* d_ws,
                              size_t ws_size, hipStream_t stream) {
  const float* u = (const float*)d_in[0];
  const float* pos = (const float*)d_in[1];
  const int* ei = (const int*)d_in[2];
  const int* batch = (const int*)d_in[3];
  const float* eW1 = (const float*)d_in[4];
  const float* eb1 = (const float*)d_in[5];
  const float* eW2 = (const float*)d_in[6];
  const float* eb2 = (const float*)d_in[7];
  const float* mW1 = (const float*)d_in[8];
  const float* mb1 = (const float*)d_in[9];
  const float* mW2 = (const float*)d_in[10];
  const float* mb2 = (const float*)d_in[11];
  const float* uW1 = (const float*)d_in[12];
  const float* ub1 = (const float*)d_in[13];
  const float* uW2 = (const float*)d_in[14];
  const float* ub2 = (const float*)d_in[15];
  const float* c1W = (const float*)d_in[16];
  const float* c1b = (const float*)d_in[17];
  const float* c2W = (const float*)d_in[18];
  const float* c2b = (const float*)d_in[19];
  const float* c3W = (const float*)d_in[20];
  const float* c3b = (const float*)d_in[21];
  float* out = (float*)d_out;

  const int* srcI = ei;
  const int* dstI = ei + NE;

  // workspace layout (doubles first for 8B alignment)
  double* statsd = (double*)d_ws;                    // 2*NBC*HC doubles
  float* h = (float*)(statsd + 2 * NBC * HC);        // NN*HC
  float* hn = h + NN * HC;                           // NN*HC
  float* agg = hn + NN * HC;                         // NN*HC
  float* rdeg = agg + NN * HC;                       // NN
  float* cntb = rdeg + NN;                           // NBC
  int* cnt = (int*)(cntb + NBC);                     // NN
  int* rowptr = cnt + NN;                            // NN+1
  int* fill = rowptr + NN + 1;                       // NN
  int* srcS = fill + NN;                             // NE
  int* dstS = srcS + NE;                             // NE

  hipMemsetAsync(cnt, 0, NN * sizeof(int), stream);
  hipMemsetAsync(cntb, 0, NBC * sizeof(float), stream);
  k_cnt<<<NE / 256, 256, 0, stream>>>(dstI, cnt);
  k_scan<<<1, 256, 0, stream>>>(cnt, rowptr, fill);
  k_scatter<<<NE / 256, 256, 0, stream>>>(srcI, dstI, fill, srcS, dstS);
  k_rdeg<<<NN / 256, 256, 0, stream>>>(rowptr, rdeg);
  k_cntb<<<NN / 256, 256, 0, stream>>>(batch, cntb);
  k_emb<<<NN / 2, 256, 0, stream>>>(u, pos, eW1, eb1, eW2, eb2, h);

  for (int l = 0; l < LC; ++l) {
    hipMemsetAsync(agg, 0, (size_t)NN * HC * sizeof(float), stream);
    hipMemsetAsync(statsd, 0, 2 * NBC * HC * sizeof(double), stream);
    k_msg<<<NE / 64, 256, 0, stream>>>(h, u, pos, srcS, dstS,
                                       mW1 + (size_t)l * MINC * HC, mb1 + l * HC,
                                       mW2 + (size_t)l * HC * HC, mb2 + l * HC,
                                       agg);
    k_upd<<<NN / 64, 256, 0, stream>>>(h, pos, agg, rdeg,
                                       uW1 + (size_t)l * UINC * HC, ub1 + l * HC,
                                       uW2 + (size_t)l * HC * HC, ub2 + l * HC,
                                       hn);
    k_stats<<<NN / 32, 256, 0, stream>>>(hn, batch, statsd);
    k_norm<<<NN * HC / 256, 256, 0, stream>>>(hn, batch, statsd, cntb, h);
  }
  k_head<<<NN, 64, 0, stream>>>(h, u, c1W, c1b, c2W, c2b, c3W, c3b, out);
}

// Round 4
// 2139.647 us; speedup vs baseline: 4.1761x; 2.1393x over previous
//
#include <hip/hip_runtime.h>

#define NN 16384
#define NE 262144
#define TWC 25
#define HC 128
#define NBC 8
#define LC 6
#define MINC 284
#define UINC 257
#define EINC 28
#define EPSC 1e-5
#define DTC 0.01f
#define SP 65  // padded LDS row stride (floats) -> conflict-free

// fp32 register-tile FMA step: 4 rows x 8 channels
#define FMA32F(ACCF, A0, A1, A2, A3, W0, W1_)                  \
  do {                                                         \
    float wv[8] = {W0.x, W0.y, W0.z, W0.w,                     \
                   W1_.x, W1_.y, W1_.z, W1_.w};                \
    float av[4] = {A0, A1, A2, A3};                            \
    _Pragma("unroll") for (int i_ = 0; i_ < 4; ++i_)           \
      _Pragma("unroll") for (int j_ = 0; j_ < 8; ++j_)         \
        ACCF[i_][j_] = fmaf(av[i_], wv[j_], ACCF[i_][j_]);     \
  } while (0)

// flush fp32 partials into fp64 accumulators (chunked accumulation)
#define FLUSH32(ACCD, ACCF)                                    \
  do {                                                         \
    _Pragma("unroll") for (int i_ = 0; i_ < 4; ++i_)           \
      _Pragma("unroll") for (int j_ = 0; j_ < 8; ++j_) {       \
        ACCD[i_][j_] += (double)ACCF[i_][j_];                  \
        ACCF[i_][j_] = 0.f;                                    \
      }                                                        \
  } while (0)

#define KSTEP(ACCF, WV, ROW, KW)                               \
  do {                                                         \
    float a0_ = sm[(ROW) * SP + e0 + 0];                       \
    float a1_ = sm[(ROW) * SP + e0 + 1];                       \
    float a2_ = sm[(ROW) * SP + e0 + 2];                       \
    float a3_ = sm[(ROW) * SP + e0 + 3];                       \
    float4 w0_ = WV[(KW) * 32 + jg * 2];                       \
    float4 w1_ = WV[(KW) * 32 + jg * 2 + 1];                   \
    FMA32F(ACCF, a0_, a1_, a2_, a3_, w0_, w1_);                \
  } while (0)

// negated-activation variant (compiles to free VOP3 input modifier)
#define KSTEPN(ACCF, WV, ROW, KW)                              \
  do {                                                         \
    float a0_ = sm[(ROW) * SP + e0 + 0];                       \
    float a1_ = sm[(ROW) * SP + e0 + 1];                       \
    float a2_ = sm[(ROW) * SP + e0 + 2];                       \
    float a3_ = sm[(ROW) * SP + e0 + 3];                       \
    float4 w0_ = WV[(KW) * 32 + jg * 2];                       \
    float4 w1_ = WV[(KW) * 32 + jg * 2 + 1];                   \
    FMA32F(ACCF, -a0_, -a1_, -a2_, -a3_, w0_, w1_);            \
  } while (0)

// ---------- preprocessing: counting sort of edges by dst ----------

__global__ __launch_bounds__(256) void k_cnt(const int* __restrict__ dst,
                                             int* __restrict__ cnt) {
  int e = blockIdx.x * 256 + threadIdx.x;
  if (e < NE) atomicAdd(&cnt[dst[e]], 1);
}

__global__ __launch_bounds__(256) void k_scan(const int* __restrict__ cnt,
                                              int* __restrict__ rowptr,
                                              int* __restrict__ fill) {
  __shared__ int part[256];
  int t = threadIdx.x;
  int s = 0;
  for (int i = 0; i < 64; ++i) s += cnt[t * 64 + i];
  part[t] = s;
  __syncthreads();
  if (t == 0) {
    int r = 0;
    for (int i = 0; i < 256; ++i) { int v = part[i]; part[i] = r; r += v; }
  }
  __syncthreads();
  int r = part[t];
  for (int i = 0; i < 64; ++i) {
    int n = t * 64 + i;
    rowptr[n] = r;
    fill[n] = r;
    r += cnt[n];
  }
  if (t == 255) rowptr[NN] = r;
}

__global__ __launch_bounds__(256) void k_scatter(const int* __restrict__ src,
                                                 const int* __restrict__ dst,
                                                 int* __restrict__ fill,
                                                 int* __restrict__ srcS,
                                                 int* __restrict__ dstS) {
  int e = blockIdx.x * 256 + threadIdx.x;
  if (e < NE) {
    int d = dst[e];
    int p = atomicAdd(&fill[d], 1);
    srcS[p] = src[e];
    dstS[p] = d;
  }
}

__global__ __launch_bounds__(256) void k_rdeg(const int* __restrict__ rowptr,
                                              float* __restrict__ rdeg) {
  int n = blockIdx.x * 256 + threadIdx.x;
  if (n < NN) {
    int c = rowptr[n + 1] - rowptr[n];
    rdeg[n] = 1.0f / (float)max(c, 1);
  }
}

__global__ __launch_bounds__(256) void k_cntb(const int* __restrict__ batch,
                                              float* __restrict__ cntb) {
  int n = blockIdx.x * 256 + threadIdx.x;
  int b = (n < NN) ? batch[n] : -1;
#pragma unroll
  for (int bb = 0; bb < NBC; ++bb) {
    unsigned long long m = __ballot(b == bb);
    if ((threadIdx.x & 63) == 0 && m != 0ULL)
      atomicAdd(&cntb[bb], (float)__popcll(m));
  }
}

// node embedding: [u(25), pos_sp(2), var(1)] -> 128 -> 128, relu both
__global__ __launch_bounds__(256) void k_emb(
    const float* __restrict__ u, const float* __restrict__ pos,
    const float* __restrict__ W1, const float* __restrict__ b1,
    const float* __restrict__ W2, const float* __restrict__ b2,
    float* __restrict__ h) {
  __shared__ float sin_[2][EINC];
  __shared__ float shid[2][HC];
  int n0 = blockIdx.x * 2;
  int t = threadIdx.x;
  if (t < 2 * EINC) {
    int e = t / EINC, c = t - e * EINC;
    int n = n0 + e;
    float v;
    if (c < TWC) v = u[n * TWC + c];
    else if (c == TWC) v = pos[n * 3 + 1];
    else if (c == TWC + 1) v = pos[n * 3 + 2];
    else v = pos[n * 3 + 0];
    sin_[e][c] = v;
  }
  __syncthreads();
  int e = t >> 7, j = t & 127;
  double acc = (double)b1[j];
  for (int k = 0; k < EINC; ++k)
    acc = fma((double)sin_[e][k], (double)W1[k * HC + j], acc);
  shid[e][j] = fmaxf((float)acc, 0.f);
  __syncthreads();
  double acc2 = (double)b2[j];
  for (int k = 0; k < HC; ++k)
    acc2 = fma((double)shid[e][k], (double)W2[k * HC + j], acc2);
  h[(n0 + e) * HC + j] = fmaxf((float)acc2, 0.f);
}

// per-node linear terms of GEMM1:
// D[n] = h@W1[0:128] + u@W1[256:281] + pos@W1[281:283] + var*W1[283] + b1
// S[n] = h@W1[128:256] - u@W1[256:281] - pos@W1[281:283]
__global__ __launch_bounds__(256) void k_node(
    const float* __restrict__ h, const float* __restrict__ u,
    const float* __restrict__ pos, const float* __restrict__ W1,
    const float* __restrict__ b1, float* __restrict__ Dv,
    float* __restrict__ Sv) {
  __shared__ float sm[156 * SP];
  const int t = threadIdx.x;
  const int n_base = blockIdx.x * 64;
  const int isS = blockIdx.y;
  const int eg = t >> 4, jg = t & 15;
  const int e0 = eg * 4, j0 = jg * 8;
  const int half = t >> 7, col = t & 127;

  // stage x = [h(128), u(25), pos_sp(2), var(1)] transposed
  for (int it = 0; it < 32; ++it) {
    int e = 2 * it + half;
    sm[col * SP + e] = h[(n_base + e) * HC + col];
  }
  for (int idx = t; idx < 64 * 28; idx += 256) {
    int e = idx / 28, c = idx - e * 28;
    int n = n_base + e;
    float v;
    if (c < TWC) v = u[n * TWC + c];
    else if (c == TWC) v = pos[n * 3 + 1];
    else if (c == TWC + 1) v = pos[n * 3 + 2];
    else v = pos[n * 3 + 0];
    sm[(128 + c) * SP + e] = v;
  }
  __syncthreads();

  float accf[4][8];
  double accd[4][8];
#pragma unroll
  for (int jj = 0; jj < 8; ++jj) {
    double bv = isS ? 0.0 : (double)b1[j0 + jj];
#pragma unroll
    for (int i = 0; i < 4; ++i) { accd[i][jj] = bv; accf[i][jj] = 0.f; }
  }

  const float4* W1v = (const float4*)W1;
  const int wb = isS ? 128 : 0;
  for (int kc = 0; kc < 128; kc += 32) {
#pragma unroll
    for (int kk = 0; kk < 32; ++kk) KSTEP(accf, W1v, kc + kk, wb + kc + kk);
    FLUSH32(accd, accf);
  }
  if (!isS) {
#pragma unroll
    for (int kk = 0; kk < 28; ++kk) KSTEP(accf, W1v, 128 + kk, 256 + kk);
  } else {
#pragma unroll
    for (int kk = 0; kk < 27; ++kk) KSTEPN(accf, W1v, 128 + kk, 256 + kk);
  }
  FLUSH32(accd, accf);

  float* outp = isS ? Sv : Dv;
#pragma unroll
  for (int i = 0; i < 4; ++i) {
    int n = n_base + e0 + i;
#pragma unroll
    for (int jj = 0; jj < 8; ++jj)
      outp[n * HC + j0 + jj] = (float)accd[i][jj];
  }
}

// per-edge: hidden = relu(D[dst]+S[src]); msg = relu(W2^T hidden);
// segmented-reduce msg into agg (dst-sorted edges)
__global__ __launch_bounds__(256) void k_msg(
    const float* __restrict__ Dv, const float* __restrict__ Sv,
    const int* __restrict__ srcS, const int* __restrict__ dstS,
    const float* __restrict__ W2, const float* __restrict__ b2,
    float* __restrict__ agg) {
  __shared__ float sm[128 * SP];  // hidden/msg [k][e]; col 64 = sdst/ssrc bits
  const int t = threadIdx.x;
  const int e_base = blockIdx.x * 64;
  const int eg = t >> 4, jg = t & 15;
  const int e0 = eg * 4, j0 = jg * 8;
  const int half = t >> 7, col = t & 127;

  if (t < 64) {
    sm[t * SP + 64] = __int_as_float(dstS[e_base + t]);
    sm[(64 + t) * SP + 64] = __int_as_float(srcS[e_base + t]);
  }
  __syncthreads();

  // stage hidden = relu(D[dst]+S[src]) transposed [k][e]
  for (int it = 0; it < 32; ++it) {
    int e = 2 * it + half;
    int nd = __float_as_int(sm[e * SP + 64]);
    int ns = __float_as_int(sm[(64 + e) * SP + 64]);
    sm[col * SP + e] = fmaxf(Dv[nd * HC + col] + Sv[ns * HC + col], 0.f);
  }
  __syncthreads();

  float accf[4][8];
  double accd[4][8];
#pragma unroll
  for (int jj = 0; jj < 8; ++jj) {
    double bv = (double)b2[j0 + jj];
#pragma unroll
    for (int i = 0; i < 4; ++i) { accd[i][jj] = bv; accf[i][jj] = 0.f; }
  }

  const float4* W2v = (const float4*)W2;
  for (int kc = 0; kc < 128; kc += 32) {
#pragma unroll
    for (int kk = 0; kk < 32; ++kk) KSTEP(accf, W2v, kc + kk, kc + kk);
    FLUSH32(accd, accf);
  }
  __syncthreads();

  // msg (relu) -> sm[j][e] (cols 0..63 only; col-64 indices survive)
#pragma unroll
  for (int jj = 0; jj < 8; ++jj) {
#pragma unroll
    for (int i = 0; i < 4; ++i)
      sm[(j0 + jj) * SP + e0 + i] = fmaxf((float)accd[i][jj], 0.f);
  }
  __syncthreads();

  // segmented reduction over sorted dst runs: one atomic per (run, channel)
  {
    int j = t & 127;
    int ebeg = (t >> 7) * 32;
    float s = 0.f;
    int cur = __float_as_int(sm[ebeg * SP + 64]);
    for (int e = ebeg; e < ebeg + 32; ++e) {
      int d = __float_as_int(sm[e * SP + 64]);  // wave-uniform broadcast
      if (d != cur) {
        atomicAdd(&agg[cur * HC + j], s);
        s = 0.f;
        cur = d;
      }
      s += sm[j * SP + e];
    }
    atomicAdd(&agg[cur * HC + j], s);
  }
}

// node update MLP 257->128->128 (relu both); hn = h + upd
__global__ __launch_bounds__(256) void k_upd(
    const float* __restrict__ h, const float* __restrict__ pos,
    const float* __restrict__ agg, const float* __restrict__ rdeg,
    const float* __restrict__ W1, const float* __restrict__ b1,
    const float* __restrict__ W2, const float* __restrict__ b2,
    float* __restrict__ hn) {
  __shared__ float sm[129 * SP];
  const int t = threadIdx.x;
  const int n_base = blockIdx.x * 64;
  const int eg = t >> 4, jg = t & 15;
  const int e0 = eg * 4, j0 = jg * 8;
  const int half = t >> 7, col = t & 127;

  float accf[4][8];
  double accd[4][8];
#pragma unroll
  for (int jj = 0; jj < 8; ++jj) {
    double bv = (double)b1[j0 + jj];
#pragma unroll
    for (int i = 0; i < 4; ++i) { accd[i][jj] = bv; accf[i][jj] = 0.f; }
  }

  // chunk A: rows 0..127 = h[n]
  for (int it = 0; it < 32; ++it) {
    int e = 2 * it + half;
    sm[col * SP + e] = h[(n_base + e) * HC + col];
  }
  __syncthreads();

  const float4* W1v = (const float4*)W1;
  for (int kc = 0; kc < 128; kc += 32) {
#pragma unroll
    for (int kk = 0; kk < 32; ++kk) KSTEP(accf, W1v, kc + kk, kc + kk);
    FLUSH32(accd, accf);
  }
  __syncthreads();

  // chunk B: rows 128..256 (local 0..128) = agg/deg (128) + var (1)
  for (int it = 0; it < 32; ++it) {
    int e = 2 * it + half;
    int n = n_base + e;
    sm[col * SP + e] = agg[n * HC + col] * rdeg[n];
  }
  if (t < 64) sm[128 * SP + t] = pos[(n_base + t) * 3 + 0];
  __syncthreads();

  for (int kc = 0; kc < 128; kc += 32) {
#pragma unroll
    for (int kk = 0; kk < 32; ++kk) KSTEP(accf, W1v, kc + kk, 128 + kc + kk);
    FLUSH32(accd, accf);
  }
  KSTEP(accf, W1v, 128, 256);
  FLUSH32(accd, accf);
  __syncthreads();

#pragma unroll
  for (int jj = 0; jj < 8; ++jj) {
#pragma unroll
    for (int i = 0; i < 4; ++i)
      sm[(j0 + jj) * SP + e0 + i] = fmaxf((float)accd[i][jj], 0.f);
  }
  __syncthreads();

#pragma unroll
  for (int jj = 0; jj < 8; ++jj) {
    double bv = (double)b2[j0 + jj];
#pragma unroll
    for (int i = 0; i < 4; ++i) { accd[i][jj] = bv; accf[i][jj] = 0.f; }
  }
  const float4* W2v = (const float4*)W2;
  for (int kc = 0; kc < 128; kc += 32) {
#pragma unroll
    for (int kk = 0; kk < 32; ++kk) KSTEP(accf, W2v, kc + kk, kc + kk);
    FLUSH32(accd, accf);
  }

#pragma unroll
  for (int i = 0; i < 4; ++i) {
    int n = n_base + e0 + i;
#pragma unroll
    for (int jj = 0; jj < 8; ++jj) {
      int j = j0 + jj;
      hn[n * HC + j] = h[n * HC + j] + fmaxf((float)accd[i][jj], 0.f);
    }
  }
}

// per-(batch,channel) sum & sumsq (fp64) with run-length accumulation
__global__ __launch_bounds__(256) void k_stats(const float* __restrict__ hn,
                                               const int* __restrict__ batch,
                                               double* __restrict__ stats) {
  int n0 = blockIdx.x * 32;
  int ch = threadIdx.x & 127;
  int rh = threadIdx.x >> 7;
  double s = 0.0, ss = 0.0;
  int cur = batch[n0 + rh];
  for (int r = rh; r < 32; r += 2) {
    int n = n0 + r;
    int b = batch[n];
    double v = (double)hn[n * HC + ch];
    if (b != cur) {
      atomicAdd(&stats[cur * HC + ch], s);
      atomicAdd(&stats[NBC * HC + cur * HC + ch], ss);
      s = 0.0; ss = 0.0; cur = b;
    }
    s += v;
    ss += v * v;
  }
  atomicAdd(&stats[cur * HC + ch], s);
  atomicAdd(&stats[NBC * HC + cur * HC + ch], ss);
}

__global__ __launch_bounds__(256) void k_norm(
    const float* __restrict__ hn, const int* __restrict__ batch,
    const double* __restrict__ stats, const float* __restrict__ cntb,
    float* __restrict__ hout) {
  int idx = blockIdx.x * 256 + threadIdx.x;
  int n = idx >> 7, ch = idx & 127;
  int b = batch[n];
  double c = fmax((double)cntb[b], 1.0);
  double mean = stats[b * HC + ch] / c;
  double ms = stats[NBC * HC + b * HC + ch] / c;
  double var = fmax(ms - mean * mean, 0.0);
  hout[idx] = (float)(((double)hn[idx] - mean) / sqrt(var + EPSC));
}

// conv head: 1x128 -> conv(8,k15,s4) relu -> conv(4,k10,s2) relu -> conv(1,k10,s1)
__global__ __launch_bounds__(64) void k_head(
    const float* __restrict__ h, const float* __restrict__ u,
    const float* __restrict__ c1W, const float* __restrict__ c1b,
    const float* __restrict__ c2W, const float* __restrict__ c2b,
    const float* __restrict__ c3W, const float* __restrict__ c3b,
    float* __restrict__ out) {
  __shared__ float hr[128];
  __shared__ float y1[8 * 29];
  __shared__ float y2[4 * 10];
  __shared__ float dv;
  int n = blockIdx.x, t = threadIdx.x;
  hr[t] = h[n * HC + t];
  hr[t + 64] = h[n * HC + 64 + t];
  __syncthreads();
  for (int idx = t; idx < 8 * 29; idx += 64) {
    int o = idx / 29, p = idx - o * 29;
    float acc = c1b[o];
    for (int q = 0; q < 15; ++q) acc = fmaf(hr[p * 4 + q], c1W[o * 15 + q], acc);
    y1[o * 29 + p] = fmaxf(acc, 0.f);
  }
  __syncthreads();
  if (t < 40) {
    int o = t / 10, p = t - o * 10;
    float acc = c2b[o];
    for (int i = 0; i < 8; ++i)
      for (int q = 0; q < 10; ++q)
        acc = fmaf(y1[i * 29 + p * 2 + q], c2W[o * 80 + i * 10 + q], acc);
    y2[o * 10 + p] = fmaxf(acc, 0.f);
  }
  __syncthreads();
  if (t == 0) {
    float acc = c3b[0];
    for (int i = 0; i < 4; ++i)
      for (int q = 0; q < 10; ++q)
        acc = fmaf(y2[i * 10 + q], c3W[i * 10 + q], acc);
    dv = acc;
  }
  __syncthreads();
  if (t < TWC) out[n * TWC + t] = u[n * TWC + 24] + DTC * (float)(t + 1) * dv;
}

extern "C" void kernel_launch(void* const* d_in, const int* in_sizes, int n_in,
                              void* d_out, int out_size, void* d_ws,
                              size_t ws_size, hipStream_t stream) {
  const float* u = (const float*)d_in[0];
  const float* pos = (const float*)d_in[1];
  const int* ei = (const int*)d_in[2];
  const int* batch = (const int*)d_in[3];
  const float* eW1 = (const float*)d_in[4];
  const float* eb1 = (const float*)d_in[5];
  const float* eW2 = (const float*)d_in[6];
  const float* eb2 = (const float*)d_in[7];
  const float* mW1 = (const float*)d_in[8];
  const float* mb1 = (const float*)d_in[9];
  const float* mW2 = (const float*)d_in[10];
  const float* mb2 = (const float*)d_in[11];
  const float* uW1 = (const float*)d_in[12];
  const float* ub1 = (const float*)d_in[13];
  const float* uW2 = (const float*)d_in[14];
  const float* ub2 = (const float*)d_in[15];
  const float* c1W = (const float*)d_in[16];
  const float* c1b = (const float*)d_in[17];
  const float* c2W = (const float*)d_in[18];
  const float* c2b = (const float*)d_in[19];
  const float* c3W = (const float*)d_in[20];
  const float* c3b = (const float*)d_in[21];
  float* out = (float*)d_out;

  const int* srcI = ei;
  const int* dstI = ei + NE;

  // workspace layout (doubles first for 8B alignment); hn aliases D
  double* statsd = (double*)d_ws;                    // 2*NBC*HC doubles
  float* h = (float*)(statsd + 2 * NBC * HC);        // NN*HC
  float* Sv = h + NN * HC;                           // NN*HC
  float* agg = Sv + NN * HC;                         // NN*HC
  float* Dhn = agg + NN * HC;                        // NN*HC (D, then hn)
  float* rdeg = Dhn + NN * HC;                       // NN
  float* cntb = rdeg + NN;                           // NBC
  int* cnt = (int*)(cntb + NBC);                     // NN
  int* rowptr = cnt + NN;                            // NN+1
  int* fill = rowptr + NN + 1;                       // NN
  int* srcS = fill + NN;                             // NE
  int* dstS = srcS + NE;                             // NE

  hipMemsetAsync(cnt, 0, NN * sizeof(int), stream);
  hipMemsetAsync(cntb, 0, NBC * sizeof(float), stream);
  k_cnt<<<NE / 256, 256, 0, stream>>>(dstI, cnt);
  k_scan<<<1, 256, 0, stream>>>(cnt, rowptr, fill);
  k_scatter<<<NE / 256, 256, 0, stream>>>(srcI, dstI, fill, srcS, dstS);
  k_rdeg<<<NN / 256, 256, 0, stream>>>(rowptr, rdeg);
  k_cntb<<<NN / 256, 256, 0, stream>>>(batch, cntb);
  k_emb<<<NN / 2, 256, 0, stream>>>(u, pos, eW1, eb1, eW2, eb2, h);

  for (int l = 0; l < LC; ++l) {
    hipMemsetAsync(agg, 0, (size_t)NN * HC * sizeof(float), stream);
    hipMemsetAsync(statsd, 0, 2 * NBC * HC * sizeof(double), stream);
    k_node<<<dim3(NN / 64, 2), 256, 0, stream>>>(
        h, u, pos, mW1 + (size_t)l * MINC * HC, mb1 + l * HC, Dhn, Sv);
    k_msg<<<NE / 64, 256, 0, stream>>>(Dhn, Sv, srcS, dstS,
                                       mW2 + (size_t)l * HC * HC, mb2 + l * HC,
                                       agg);
    k_upd<<<NN / 64, 256, 0, stream>>>(h, pos, agg, rdeg,
                                       uW1 + (size_t)l * UINC * HC, ub1 + l * HC,
                                       uW2 + (size_t)l * HC * HC, ub2 + l * HC,
                                       Dhn);
    k_stats<<<NN / 32, 256, 0, stream>>>(Dhn, batch, statsd);
    k_norm<<<NN * HC / 256, 256, 0, stream>>>(Dhn, batch, statsd, cntb, h);
  }
  k_head<<<NN, 64, 0, stream>>>(h, u, c1W, c1b, c2W, c2b, c3W, c3b, out);
}